// Round 1
// baseline (313.600 us; speedup 1.0000x reference)
//
#include <hip/hip_runtime.h>
#include <hip/hip_bf16.h>
#include <stdint.h>

#define N_TOT   16384
#define N_LB    2048
#define C_DIM   100

typedef __attribute__((ext_vector_type(8))) short s16x8;
typedef __attribute__((ext_vector_type(4))) float f32x4;

#if __has_builtin(__builtin_amdgcn_exp2f)
#define EXP2F __builtin_amdgcn_exp2f
#else
#define EXP2F exp2f
#endif

__device__ __forceinline__ short f2bf(float x) {
  union { float f; unsigned u; } v; v.f = x;
  unsigned r = (v.u + 0x7fffu + ((v.u >> 16) & 1u)) >> 16;
  return (short)r;
}

// ---------------- Kernel A: l2-normalize feats -> bf16, tiled+swizzled ----------------
// feats_ws layout: tile kt (16 rows), row q (=r&15): 16 slots of 8 bf16;
// slot s (dims 8s..8s+7) stored at position (s ^ q)  -> conflict-free ds_read_b128.
__global__ void k_norm(const float* __restrict__ lb, const float* __restrict__ anc,
                       const float* __restrict__ pos, short* __restrict__ feats_ws) {
  const int r = blockIdx.x, d = threadIdx.x;  // 128 threads
  const float* src = (r < N_LB) ? (lb + (size_t)r * 128)
                   : ((r < 9216) ? (anc + (size_t)(r - 2048) * 128)
                                 : (pos + (size_t)(r - 9216) * 128));
  float x = src[d];
  float ss = x * x;
  #pragma unroll
  for (int o = 32; o; o >>= 1) ss += __shfl_xor(ss, o);
  __shared__ float red[2];
  if ((d & 63) == 0) red[d >> 6] = ss;
  __syncthreads();
  float n = sqrtf(red[0] + red[1]);
  float scale = 1.0f / fmaxf(n, 1e-12f);
  const int kt = r >> 4, q = r & 15;
  feats_ws[(size_t)kt * 2048 + q * 128 + (((d >> 3) ^ q) << 3) + (d & 7)] = f2bf(x * scale);
}

// ---------------- Kernel B: class_val (one-hot rows + softmax rows) -> bf16, PV B-frag order ----
// v_ws layout per 32-row tile T: [ch 0..7][g 0..3][sq=q^(4g) 0..15][jj 0..7]
// jj<4 -> row 32T+4g+jj ; jj>=4 -> row 32T+16+4g+(jj-4). col = 16*ch + q.
__global__ void k_classval(const float* __restrict__ onehot, const float* __restrict__ lg1,
                           const float* __restrict__ lg2, short* __restrict__ v_ws) {
  const int r = blockIdx.x, c = threadIdx.x;  // 128 threads, cols 0..127 (>=100 zero-pad)
  const int T = r >> 5, rr = r & 31;
  const int jj = (((rr >> 4) & 1) << 2) | (rr & 3);
  const int g = (rr & 15) >> 2;
  const int ch = c >> 4, q = c & 15;
  const size_t off = (size_t)T * 4096 + ch * 512 + g * 128 + (size_t)((q ^ (g << 2)) << 3) + jj;
  __shared__ float red[2];
  float v;
  if (r < N_LB) {
    v = (c < C_DIM) ? onehot[(size_t)r * C_DIM + c] : 0.f;
  } else {
    const float* lr = (r < 9216) ? (lg1 + (size_t)(r - 2048) * C_DIM)
                                 : (lg2 + (size_t)(r - 9216) * C_DIM);
    float x = (c < C_DIM) ? lr[c] : -3e38f;
    float m = x;
    #pragma unroll
    for (int o = 32; o; o >>= 1) m = fmaxf(m, __shfl_xor(m, o));
    if ((c & 63) == 0) red[c >> 6] = m;
    __syncthreads();
    m = fmaxf(red[0], red[1]);
    float e = (c < C_DIM) ? EXP2F((x - m) * 1.44269504f) : 0.f;
    float s = e;
    #pragma unroll
    for (int o = 32; o; o >>= 1) s += __shfl_xor(s, o);
    __syncthreads();
    if ((c & 63) == 0) red[c >> 6] = s;
    __syncthreads();
    v = e / (red[0] + red[1]);
  }
  v_ws[off] = f2bf(v);
}

// ---------------- Kernel C: attention ----------------
__device__ __forceinline__ void stage_pair(const short* kg, const short* vg,
                                           short* lk, short* lv, int wave, int lane) {
  #pragma unroll
  for (int i = 0; i < 2; ++i) {
    const int blk = wave * 2 + i;  // 8 chunks of 1KB per 8KB tile
    __builtin_amdgcn_global_load_lds(
        (const __attribute__((address_space(1))) void*)(kg + blk * 512 + lane * 8),
        (__attribute__((address_space(3))) void*)(lk + blk * 512), 16, 0, 0);
    __builtin_amdgcn_global_load_lds(
        (const __attribute__((address_space(1))) void*)(vg + blk * 512 + lane * 8),
        (__attribute__((address_space(3))) void*)(lv + blk * 512), 16, 0, 0);
  }
}

__global__ __launch_bounds__(256) void k_attn(const short* __restrict__ feats,
                                              const short* __restrict__ vws,
                                              float* __restrict__ out) {
  __shared__ __align__(16) short lds[2][8192];  // per buf: 4096 K shorts + 4096 V shorts
  const int tid = threadIdx.x;
  const int wave = tid >> 6, lane = tid & 63;
  const int q = lane & 15, g = lane >> 4;
  const int qt = blockIdx.x * 4 + wave;  // Q tile of 16 rows, 0..1023

  // Q fragments (B operand of swapped QK^T): Q[row=q][k = 32kk + 8g + j]
  s16x8 bQ[4];
  #pragma unroll
  for (int kk = 0; kk < 4; ++kk)
    bQ[kk] = *(const s16x8*)(feats + (size_t)qt * 2048 + q * 128 + ((((kk << 2) | g) ^ q) << 3));

  f32x4 oacc[7];
  #pragma unroll
  for (int c = 0; c < 7; ++c) oacc[c] = (f32x4){0.f, 0.f, 0.f, 0.f};
  float lsum = 0.f;

  stage_pair(feats, vws, lds[0], lds[0] + 4096, wave, lane);
  __syncthreads();

  for (int t = 0; t < 512; ++t) {  // 512 K-pair tiles of 32 rows
    const int cur = t & 1;
    if (t + 1 < 512)
      stage_pair(feats + (size_t)(t + 1) * 4096, vws + (size_t)(t + 1) * 4096,
                 lds[cur ^ 1], lds[cur ^ 1] + 4096, wave, lane);
    const short* lk = lds[cur];
    const short* lv = lds[cur] + 4096;

    s16x8 aK0[4], aK1[4];
    #pragma unroll
    for (int kk = 0; kk < 4; ++kk) {
      const int off = q * 128 + ((((kk << 2) | g) ^ q) << 3);
      aK0[kk] = *(const s16x8*)(lk + off);
      aK1[kk] = *(const s16x8*)(lk + 2048 + off);
    }
    // swapped QK^T: D[krow][qcol] -> lane holds S[q=lane&15][klocal = 4g + reg]
    f32x4 s0 = {0.f, 0.f, 0.f, 0.f}, s1 = {0.f, 0.f, 0.f, 0.f};
    #pragma unroll
    for (int kk = 0; kk < 4; ++kk) {
      s0 = __builtin_amdgcn_mfma_f32_16x16x32_bf16(aK0[kk], bQ[kk], s0, 0, 0, 0);
      s1 = __builtin_amdgcn_mfma_f32_16x16x32_bf16(aK1[kk], bQ[kk], s1, 0, 0, 0);
    }
    // p = exp(10 s - 10); max score is exactly 10 (diagonal, normalized feats)
    s16x8 pf;
    float ps = 0.f;
    #pragma unroll
    for (int r = 0; r < 4; ++r) {
      float p0 = EXP2F(s0[r] * 14.4269504f - 14.4269504f);
      float p1 = EXP2F(s1[r] * 14.4269504f - 14.4269504f);
      ps += p0 + p1;
      pf[r]     = f2bf(p0);   // A-frag k = 8g + r      -> K row 4g+r   (tile even)
      pf[r + 4] = f2bf(p1);   // A-frag k = 8g + 4 + r  -> K row 16+4g+r (tile odd)
    }
    lsum += ps;
    // PV: oacc[ch] += P (16x32) * V (32x16); V pre-permuted to match A-frag k order
    #pragma unroll
    for (int c = 0; c < 7; ++c) {
      s16x8 bV = *(const s16x8*)(lv + c * 512 + g * 128 + ((q ^ (g << 2)) << 3));
      oacc[c] = __builtin_amdgcn_mfma_f32_16x16x32_bf16(pf, bV, oacc[c], 0, 0, 0);
    }
    __syncthreads();
  }

  // full row-sum for q = lane&15 (combine the 4 lane-groups)
  lsum += __shfl_xor(lsum, 16);
  lsum += __shfl_xor(lsum, 32);
  float linv[4];
  #pragma unroll
  for (int r = 0; r < 4; ++r) linv[r] = 1.0f / __shfl(lsum, (g << 2) | r);

  const int row0 = qt * 16;
  #pragma unroll
  for (int c = 0; c < 7; ++c) {
    const int col = c * 16 + q;
    if (col < C_DIM) {
      #pragma unroll
      for (int r = 0; r < 4; ++r)
        out[(size_t)(row0 + (g << 2) + r) * C_DIM + col] = oacc[c][r] * linv[r];
    }
  }
}

extern "C" void kernel_launch(void* const* d_in, const int* in_sizes, int n_in,
                              void* d_out, int out_size, void* d_ws, size_t ws_size,
                              hipStream_t stream) {
  const float* anchor   = (const float*)d_in[0];  // 7168x128
  const float* positive = (const float*)d_in[1];  // 7168x128
  const float* lb_feat  = (const float*)d_in[2];  // 2048x128
  const float* lb_onehot= (const float*)d_in[3];  // 2048x100
  // d_in[4] logits_x_lb: only shape used by reference
  const float* lg1      = (const float*)d_in[5];  // 7168x100
  const float* lg2      = (const float*)d_in[6];  // 7168x100
  float* out = (float*)d_out;

  short* feats_ws = (short*)d_ws;              // 16384*128 bf16 = 4MB
  short* v_ws     = feats_ws + 2097152;        // 16384*128 bf16 = 4MB

  // passthrough copies (output order: anchor, positive, lb_feat, lb_one_hot, ...)
  hipMemcpyAsync(out,            anchor,   (size_t)917504 * 4, hipMemcpyDeviceToDevice, stream);
  hipMemcpyAsync(out + 917504,   positive, (size_t)917504 * 4, hipMemcpyDeviceToDevice, stream);
  hipMemcpyAsync(out + 1835008,  lb_feat,  (size_t)262144 * 4, hipMemcpyDeviceToDevice, stream);
  hipMemcpyAsync(out + 2097152,  lb_onehot,(size_t)204800 * 4, hipMemcpyDeviceToDevice, stream);

  k_norm    <<<16384, 128, 0, stream>>>(lb_feat, anchor, positive, feats_ws);
  k_classval<<<16384, 128, 0, stream>>>(lb_onehot, lg1, lg2, v_ws);
  // out_lb / ulb1 / ulb2 are contiguous: rows 0..16384, 100 cols, starting at 2301952
  k_attn    <<<256, 256, 0, stream>>>(feats_ws, v_ws, out + 2301952);
}

// Round 2
// 172.151 us; speedup vs baseline: 1.8217x; 1.8217x over previous
//
#include <hip/hip_runtime.h>
#include <hip/hip_bf16.h>
#include <stdint.h>

#define N_TOT   16384
#define N_LB    2048
#define C_DIM   100

typedef __attribute__((ext_vector_type(8))) short s16x8;
typedef __attribute__((ext_vector_type(4))) float f32x4;

#if __has_builtin(__builtin_amdgcn_exp2f)
#define EXP2F __builtin_amdgcn_exp2f
#else
#define EXP2F exp2f
#endif

__device__ __forceinline__ short f2bf(float x) {
  union { float f; unsigned u; } v; v.f = x;
  unsigned r = (v.u + 0x7fffu + ((v.u >> 16) & 1u)) >> 16;
  return (short)r;
}
__device__ __forceinline__ float bf2f(short h) {
  union { unsigned u; float f; } v; v.u = ((unsigned)(unsigned short)h) << 16; return v.f;
}
// slot swizzle: XOR q's low bits AND bit3 (into bank bits) -> q vs q+8 hit different banks
__device__ __forceinline__ int slotsw(int c, int q) {
  return (c ^ q ^ ((q & 8) >> 1)) & 15;
}
__device__ __forceinline__ unsigned cvtpk_bf16(float a, float b) {
  unsigned r;
  asm("v_cvt_pk_bf16_f32 %0, %1, %2" : "=v"(r) : "v"(a), "v"(b));
  return r;
}

// ---------------- Kernel A: l2-normalize feats -> bf16, tiled+swizzled ----------------
__global__ void k_norm(const float* __restrict__ lb, const float* __restrict__ anc,
                       const float* __restrict__ pos, short* __restrict__ feats_ws) {
  const int r = blockIdx.x, d = threadIdx.x;  // 128 threads
  const float* src = (r < N_LB) ? (lb + (size_t)r * 128)
                   : ((r < 9216) ? (anc + (size_t)(r - 2048) * 128)
                                 : (pos + (size_t)(r - 9216) * 128));
  float x = src[d];
  float ss = x * x;
  #pragma unroll
  for (int o = 32; o; o >>= 1) ss += __shfl_xor(ss, o);
  __shared__ float red[2];
  if ((d & 63) == 0) red[d >> 6] = ss;
  __syncthreads();
  float n = sqrtf(red[0] + red[1]);
  float scale = 1.0f / fmaxf(n, 1e-12f);
  const int kt = r >> 4, q = r & 15;
  feats_ws[(size_t)kt * 2048 + q * 128 + (slotsw(d >> 3, q) << 3) + (d & 7)] = f2bf(x * scale);
}

// ---------------- Kernel B: class_val -> bf16, PV B-frag order ----------------
__global__ void k_classval(const float* __restrict__ onehot, const float* __restrict__ lg1,
                           const float* __restrict__ lg2, short* __restrict__ v_ws) {
  const int r = blockIdx.x, c = threadIdx.x;  // 128 threads
  const int T = r >> 5, rr = r & 31;
  const int jj = (((rr >> 4) & 1) << 2) | (rr & 3);
  const int g = (rr & 15) >> 2;
  const int ch = c >> 4, q = c & 15;
  const size_t off = (size_t)T * 4096 + ch * 512 + g * 128 + (size_t)((q ^ (g << 2)) << 3) + jj;
  __shared__ float red[2];
  float v;
  if (r < N_LB) {
    v = (c < C_DIM) ? onehot[(size_t)r * C_DIM + c] : 0.f;
  } else {
    const float* lr = (r < 9216) ? (lg1 + (size_t)(r - 2048) * C_DIM)
                                 : (lg2 + (size_t)(r - 9216) * C_DIM);
    float x = (c < C_DIM) ? lr[c] : -3e38f;
    float m = x;
    #pragma unroll
    for (int o = 32; o; o >>= 1) m = fmaxf(m, __shfl_xor(m, o));
    if ((c & 63) == 0) red[c >> 6] = m;
    __syncthreads();
    m = fmaxf(red[0], red[1]);
    float e = (c < C_DIM) ? EXP2F((x - m) * 1.44269504f) : 0.f;
    float s = e;
    #pragma unroll
    for (int o = 32; o; o >>= 1) s += __shfl_xor(s, o);
    __syncthreads();
    if ((c & 63) == 0) red[c >> 6] = s;
    __syncthreads();
    v = e / (red[0] + red[1]);
  }
  v_ws[off] = f2bf(v);
}

// ---------------- Kernel C: attention, 32 Q rows/wave, K-split across blocks ----------------
__device__ __forceinline__ void stage_k(const short* kg, short* dst, int wave, int lane) {
  #pragma unroll
  for (int i = 0; i < 2; ++i) {
    const int blk = wave * 2 + i;  // 8 chunks of 1KB per 8KB K-tile
    __builtin_amdgcn_global_load_lds(
        (const __attribute__((address_space(1))) void*)(kg + blk * 512 + lane * 8),
        (__attribute__((address_space(3))) void*)(dst + blk * 512), 16, 0, 0);
  }
}

__global__ __launch_bounds__(256, 2) void k_attn(const short* __restrict__ feats,
                                                 const short* __restrict__ vws,
                                                 short* __restrict__ pO,
                                                 float* __restrict__ pL,
                                                 float* __restrict__ outp,
                                                 int S, int nt) {
  __shared__ __align__(16) short lk[2][4096];  // K only, double-buffered (16 KB)
  const int tid = threadIdx.x;
  const int wave = tid >> 6, lane = tid & 63;
  const int q = lane & 15, g = lane >> 4;
  const int bid = blockIdx.x;
  const int slice = bid % S;                  // consecutive bids -> XCD round-robin: slice==XCD
  const int qsup = (bid / S) * 4 + wave;      // 32-row Q super-tile, 0..511
  const int t0 = slice * nt;                  // first 32-row K-tile of this slice

  // Q fragments for 2 sets of 16 rows
  s16x8 bQ[2][4];
  #pragma unroll
  for (int set = 0; set < 2; ++set)
    #pragma unroll
    for (int kk = 0; kk < 4; ++kk)
      bQ[set][kk] = *(const s16x8*)(feats + (size_t)(qsup * 2 + set) * 2048 + q * 128 +
                                    (slotsw((kk << 2) | g, q) << 3));

  f32x4 oacc[2][7];
  #pragma unroll
  for (int set = 0; set < 2; ++set)
    #pragma unroll
    for (int c = 0; c < 7; ++c) oacc[set][c] = (f32x4){0.f, 0.f, 0.f, 0.f};
  float lsum[2] = {0.f, 0.f};

  stage_k(feats + (size_t)t0 * 4096, lk[0], wave, lane);
  __syncthreads();

  for (int t = 0; t < nt; ++t) {
    const int cur = t & 1;
    if (t + 1 < nt)
      stage_k(feats + (size_t)(t0 + t + 1) * 4096, lk[cur ^ 1], wave, lane);

    s16x8 aK0[4], aK1[4];
    #pragma unroll
    for (int kk = 0; kk < 4; ++kk) {
      const int off = q * 128 + (slotsw((kk << 2) | g, q) << 3);
      aK0[kk] = *(const s16x8*)(&lk[cur][off]);
      aK1[kk] = *(const s16x8*)(&lk[cur][2048 + off]);
    }
    // V fragments straight from global (L1/L2-resident; identical across the 4 waves)
    const short* vbase = vws + (size_t)(t0 + t) * 4096 + g * 128 + ((q ^ (g << 2)) << 3);
    s16x8 bV[7];
    #pragma unroll
    for (int c = 0; c < 7; ++c) bV[c] = *(const s16x8*)(vbase + c * 512);

    // swapped QK^T for both Q-sets (aK shared)
    f32x4 s0[2] = {{0.f,0.f,0.f,0.f},{0.f,0.f,0.f,0.f}};
    f32x4 s1[2] = {{0.f,0.f,0.f,0.f},{0.f,0.f,0.f,0.f}};
    #pragma unroll
    for (int kk = 0; kk < 4; ++kk)
      #pragma unroll
      for (int set = 0; set < 2; ++set) {
        s0[set] = __builtin_amdgcn_mfma_f32_16x16x32_bf16(aK0[kk], bQ[set][kk], s0[set], 0, 0, 0);
        s1[set] = __builtin_amdgcn_mfma_f32_16x16x32_bf16(aK1[kk], bQ[set][kk], s1[set], 0, 0, 0);
      }

    // p = exp(10 s - 10); pack to bf16 A-frags via v_cvt_pk
    s16x8 pf[2];
    #pragma unroll
    for (int set = 0; set < 2; ++set) {
      float p[8];
      float ps = 0.f;
      #pragma unroll
      for (int r = 0; r < 4; ++r) {
        p[r]     = EXP2F(s0[set][r] * 14.4269504f - 14.4269504f);
        p[r + 4] = EXP2F(s1[set][r] * 14.4269504f - 14.4269504f);
        ps += p[r] + p[r + 4];
      }
      lsum[set] += ps;
      union { unsigned w[4]; s16x8 h; } pu;
      pu.w[0] = cvtpk_bf16(p[0], p[1]);
      pu.w[1] = cvtpk_bf16(p[2], p[3]);
      pu.w[2] = cvtpk_bf16(p[4], p[5]);
      pu.w[3] = cvtpk_bf16(p[6], p[7]);
      pf[set] = pu.h;
    }

    // PV: each bV feeds both Q-sets
    #pragma unroll
    for (int c = 0; c < 7; ++c)
      #pragma unroll
      for (int set = 0; set < 2; ++set)
        oacc[set][c] = __builtin_amdgcn_mfma_f32_16x16x32_bf16(pf[set], bV[c], oacc[set][c], 0, 0, 0);

    __syncthreads();
  }

  // epilogue: write partials (or final when S==1)
  #pragma unroll
  for (int set = 0; set < 2; ++set) {
    float ls = lsum[set];
    ls += __shfl_xor(ls, 16);
    ls += __shfl_xor(ls, 32);
    const int row0 = qsup * 32 + set * 16;
    if (S == 1) {
      float linv[4];
      #pragma unroll
      for (int r = 0; r < 4; ++r) linv[r] = 1.0f / __shfl(ls, (g << 2) | r);
      #pragma unroll
      for (int c = 0; c < 7; ++c) {
        const int col = c * 16 + q;
        if (col < C_DIM)
          #pragma unroll
          for (int r = 0; r < 4; ++r)
            outp[(size_t)(row0 + (g << 2) + r) * C_DIM + col] = oacc[set][c][r] * linv[r];
      }
    } else {
      if (lane < 16) pL[(size_t)slice * N_TOT + row0 + lane] = ls;
      #pragma unroll
      for (int c = 0; c < 7; ++c)
        #pragma unroll
        for (int r = 0; r < 4; ++r)
          pO[((size_t)slice * N_TOT + row0 + (g << 2) + r) * 112 + c * 16 + q] =
              f2bf(oacc[set][c][r]);
    }
  }
}

// ---------------- Kernel D: combine K-split partials ----------------
__global__ void k_combine(const short* __restrict__ pO, const float* __restrict__ pL,
                          float* __restrict__ out, int S) {
  const int row = blockIdx.x * 2 + (threadIdx.x >> 7);
  const int c = threadIdx.x & 127;
  float l = 0.f, o = 0.f;
  for (int s = 0; s < S; ++s) {
    l += pL[(size_t)s * N_TOT + row];
    if (c < 112) o += bf2f(pO[((size_t)s * N_TOT + row) * 112 + c]);
  }
  if (c < C_DIM) out[(size_t)row * C_DIM + c] = o / l;
}

extern "C" void kernel_launch(void* const* d_in, const int* in_sizes, int n_in,
                              void* d_out, int out_size, void* d_ws, size_t ws_size,
                              hipStream_t stream) {
  const float* anchor   = (const float*)d_in[0];  // 7168x128
  const float* positive = (const float*)d_in[1];  // 7168x128
  const float* lb_feat  = (const float*)d_in[2];  // 2048x128
  const float* lb_onehot= (const float*)d_in[3];  // 2048x100
  const float* lg1      = (const float*)d_in[5];  // 7168x100
  const float* lg2      = (const float*)d_in[6];  // 7168x100
  float* out = (float*)d_out;

  short* feats_ws = (short*)d_ws;              // 4 MB
  short* v_ws     = feats_ws + 2097152;        // 4 MB
  float* pL       = (float*)(v_ws + 2097152);  // 8 slices max: 512 KB
  short* pO       = (short*)(pL + 8 * N_TOT);  // S * 16384 * 112 * 2B

  // pick largest power-of-2 K-split that fits the workspace
  int S = 8;
  while (S > 1 && 8912896ull + (size_t)S * N_TOT * 112 * 2 > ws_size) S >>= 1;
  const int nt = 512 / S;

  // passthrough copies (output order: anchor, positive, lb_feat, lb_one_hot, ...)
  hipMemcpyAsync(out,            anchor,   (size_t)917504 * 4, hipMemcpyDeviceToDevice, stream);
  hipMemcpyAsync(out + 917504,   positive, (size_t)917504 * 4, hipMemcpyDeviceToDevice, stream);
  hipMemcpyAsync(out + 1835008,  lb_feat,  (size_t)262144 * 4, hipMemcpyDeviceToDevice, stream);
  hipMemcpyAsync(out + 2097152,  lb_onehot,(size_t)204800 * 4, hipMemcpyDeviceToDevice, stream);

  k_norm    <<<16384, 128, 0, stream>>>(lb_feat, anchor, positive, feats_ws);
  k_classval<<<16384, 128, 0, stream>>>(lb_onehot, lg1, lg2, v_ws);

  float* attn_out = out + 2301952;
  k_attn<<<128 * S, 256, 0, stream>>>(feats_ws, v_ws, pO, pL, attn_out, S, nt);
  if (S > 1)
    k_combine<<<N_TOT / 2, 256, 0, stream>>>(pO, pL, attn_out, S);
}

// Round 3
// 149.724 us; speedup vs baseline: 2.0945x; 1.1498x over previous
//
#include <hip/hip_runtime.h>
#include <hip/hip_bf16.h>
#include <stdint.h>

#define N_TOT   16384
#define N_LB    2048
#define C_DIM   100

typedef __attribute__((ext_vector_type(8))) short s16x8;
typedef __attribute__((ext_vector_type(4))) float f32x4;

#if __has_builtin(__builtin_amdgcn_exp2f)
#define EXP2F __builtin_amdgcn_exp2f
#else
#define EXP2F exp2f
#endif

__device__ __forceinline__ short f2bf(float x) {
  union { float f; unsigned u; } v; v.f = x;
  unsigned r = (v.u + 0x7fffu + ((v.u >> 16) & 1u)) >> 16;
  return (short)r;
}
__device__ __forceinline__ float bf2f(short h) {
  union { unsigned u; float f; } v; v.u = ((unsigned)(unsigned short)h) << 16; return v.f;
}
__device__ __forceinline__ int slotsw(int c, int q) {
  return (c ^ q ^ ((q & 8) >> 1)) & 15;
}
__device__ __forceinline__ unsigned cvtpk_bf16(float a, float b) {
  unsigned r;
  asm("v_cvt_pk_bf16_f32 %0, %1, %2" : "=v"(r) : "v"(a), "v"(b));
  return r;
}

// ---------------- Kernel P: fused prep (normalize + classval + passthrough copies) ----
__global__ __launch_bounds__(256) void k_prep(const float* __restrict__ anc,
                                              const float* __restrict__ pos,
                                              const float* __restrict__ lbf,
                                              const float* __restrict__ onehot,
                                              const float* __restrict__ lg1,
                                              const float* __restrict__ lg2,
                                              short* __restrict__ feats_ws,
                                              short* __restrict__ v_ws,
                                              float* __restrict__ out) {
  const int bid = blockIdx.x, tid = threadIdx.x;
  const int wid = tid >> 6, lane = tid & 63;
  if (bid < 4096) {
    // ---- l2-normalize, one wave per row ----
    const int r = bid * 4 + wid;
    const float* src = (r < N_LB) ? (lbf + (size_t)r * 128)
                     : ((r < 9216) ? (anc + (size_t)(r - 2048) * 128)
                                   : (pos + (size_t)(r - 9216) * 128));
    float2 x = *(const float2*)(src + lane * 2);
    float ss = x.x * x.x + x.y * x.y;
    #pragma unroll
    for (int o = 32; o; o >>= 1) ss += __shfl_xor(ss, o);
    float scale = rsqrtf(fmaxf(ss, 1e-24f));
    const int kt = r >> 4, q = r & 15;
    union { short s[2]; unsigned u; } w;
    w.s[0] = f2bf(x.x * scale);
    w.s[1] = f2bf(x.y * scale);
    *(unsigned*)(feats_ws + (size_t)kt * 2048 + q * 128 +
                 (slotsw(lane >> 2, q) << 3) + ((lane & 3) << 1)) = w.u;
  } else if (bid < 8192) {
    // ---- class_val rows, one wave per row; col 112 = 1.0 (lsum ones-column) ----
    const int r = (bid - 4096) * 4 + wid;
    const int c0 = lane, c1 = lane + 64;
    float v0, v1;
    if (r < N_LB) {
      v0 = (c0 < C_DIM) ? onehot[(size_t)r * C_DIM + c0] : 0.f;
      v1 = (c1 < C_DIM) ? onehot[(size_t)r * C_DIM + c1] : 0.f;
    } else {
      const float* lr = (r < 9216) ? (lg1 + (size_t)(r - 2048) * C_DIM)
                                   : (lg2 + (size_t)(r - 9216) * C_DIM);
      float x0 = (c0 < C_DIM) ? lr[c0] : -3e38f;
      float x1 = (c1 < C_DIM) ? lr[c1] : -3e38f;
      float m = fmaxf(x0, x1);
      #pragma unroll
      for (int o = 32; o; o >>= 1) m = fmaxf(m, __shfl_xor(m, o));
      float e0 = (c0 < C_DIM) ? EXP2F((x0 - m) * 1.44269504f) : 0.f;
      float e1 = (c1 < C_DIM) ? EXP2F((x1 - m) * 1.44269504f) : 0.f;
      float s = e0 + e1;
      #pragma unroll
      for (int o = 32; o; o >>= 1) s += __shfl_xor(s, o);
      float inv = 1.0f / s;
      v0 = e0 * inv;
      v1 = e1 * inv;
    }
    if (c1 == 112) v1 = 1.0f;
    const int T = r >> 5, rr = r & 31;
    const int jj = (((rr >> 4) & 1) << 2) | (rr & 3);
    const int gg = (rr & 15) >> 2;
    {
      const int ch = c0 >> 4, qq = c0 & 15;
      v_ws[(size_t)T * 4096 + ch * 512 + gg * 128 + ((qq ^ (gg << 2)) << 3) + jj] = f2bf(v0);
    }
    {
      const int ch = c1 >> 4, qq = c1 & 15;
      v_ws[(size_t)T * 4096 + ch * 512 + gg * 128 + ((qq ^ (gg << 2)) << 3) + jj] = f2bf(v1);
    }
  } else {
    // ---- passthrough copies: 2301952 floats as float4 ----
    const long long i4 = (long long)(bid - 8192) * 256 + tid;  // 575488 total
    const long long f = i4 * 4;
    float4 v;
    if (f < 917504)        v = *(const float4*)(anc + f);
    else if (f < 1835008)  v = *(const float4*)(pos + (f - 917504));
    else if (f < 2097152)  v = *(const float4*)(lbf + (f - 1835008));
    else                   v = *(const float4*)(onehot + (f - 2097152));
    *(float4*)(out + f) = v;
  }
}

// ---------------- Kernel C: attention ----------------
__device__ __forceinline__ void stage64(const short* kg, short* dst, int wave, int lane) {
  #pragma unroll
  for (int i = 0; i < 4; ++i) {
    const int blk = wave * 4 + i;  // 16 chunks of 1KB per 16KB tile (64 rows)
    __builtin_amdgcn_global_load_lds(
        (const __attribute__((address_space(1))) void*)(kg + blk * 512 + lane * 8),
        (__attribute__((address_space(3))) void*)(dst + blk * 512), 16, 0, 0);
  }
}

__global__ __launch_bounds__(256, 2) void k_attn(const short* __restrict__ feats,
                                                 const short* __restrict__ vws,
                                                 short* __restrict__ pO,
                                                 float* __restrict__ pL,
                                                 float* __restrict__ outp,
                                                 int S, int nt2) {
  __shared__ __align__(16) short lk[2][8192];  // two 64-row K buffers (16KB each)
  const int tid = threadIdx.x;
  const int wave = tid >> 6, lane = tid & 63;
  const int q = lane & 15, g = lane >> 4;
  const int bid = blockIdx.x;
  const int slice = bid % S;            // consecutive bids round-robin XCDs: slice==XCD
  const int qsup = (bid / S) * 4 + wave;
  const int t0h = slice * nt2;          // 64-row tile units

  s16x8 bQ[2][4];
  #pragma unroll
  for (int set = 0; set < 2; ++set)
    #pragma unroll
    for (int kk = 0; kk < 4; ++kk)
      bQ[set][kk] = *(const s16x8*)(feats + (size_t)(qsup * 2 + set) * 2048 + q * 128 +
                                    (slotsw((kk << 2) | g, q) << 3));

  f32x4 zero = {0.f, 0.f, 0.f, 0.f};
  f32x4 oacc[2][8];
  #pragma unroll
  for (int set = 0; set < 2; ++set)
    #pragma unroll
    for (int c = 0; c < 8; ++c) oacc[set][c] = zero;

  int dso[4];
  #pragma unroll
  for (int kk = 0; kk < 4; ++kk) dso[kk] = q * 128 + (slotsw((kk << 2) | g, q) << 3);
  const int vfo = g * 128 + ((q ^ (g << 2)) << 3);

  stage64(feats + (size_t)t0h * 8192, lk[0], wave, lane);
  __syncthreads();

  for (int t = 0; t < nt2; ++t) {
    const int cur = t & 1;
    if (t + 1 < nt2)
      stage64(feats + (size_t)(t0h + t + 1) * 8192, lk[cur ^ 1], wave, lane);
    const short* lkc = lk[cur];
    const short* vb = vws + (size_t)(t0h + t) * 8192 + vfo;

    // ---- sub0: aK reads + QK ----
    s16x8 aK0[4], aK1[4];
    #pragma unroll
    for (int kk = 0; kk < 4; ++kk) {
      aK0[kk] = *(const s16x8*)(lkc + dso[kk]);
      aK1[kk] = *(const s16x8*)(lkc + 2048 + dso[kk]);
    }
    f32x4 sA0[2] = {zero, zero}, sA1[2] = {zero, zero};
    __builtin_amdgcn_s_setprio(1);
    #pragma unroll
    for (int kk = 0; kk < 4; ++kk)
      #pragma unroll
      for (int set = 0; set < 2; ++set) {
        sA0[set] = __builtin_amdgcn_mfma_f32_16x16x32_bf16(aK0[kk], bQ[set][kk], sA0[set], 0, 0, 0);
        sA1[set] = __builtin_amdgcn_mfma_f32_16x16x32_bf16(aK1[kk], bQ[set][kk], sA1[set], 0, 0, 0);
      }
    __builtin_amdgcn_s_setprio(0);

    // ---- bV sub0 (global, L2-resident) ----
    s16x8 bV0[8];
    #pragma unroll
    for (int c = 0; c < 8; ++c) bV0[c] = *(const s16x8*)(vb + c * 512);

    // ---- sub1: aK reads + QK (overlaps exp0 below) ----
    s16x8 bK0[4], bK1[4];
    #pragma unroll
    for (int kk = 0; kk < 4; ++kk) {
      bK0[kk] = *(const s16x8*)(lkc + 4096 + dso[kk]);
      bK1[kk] = *(const s16x8*)(lkc + 6144 + dso[kk]);
    }
    f32x4 sB0[2] = {zero, zero}, sB1[2] = {zero, zero};
    __builtin_amdgcn_s_setprio(1);
    #pragma unroll
    for (int kk = 0; kk < 4; ++kk)
      #pragma unroll
      for (int set = 0; set < 2; ++set) {
        sB0[set] = __builtin_amdgcn_mfma_f32_16x16x32_bf16(bK0[kk], bQ[set][kk], sB0[set], 0, 0, 0);
        sB1[set] = __builtin_amdgcn_mfma_f32_16x16x32_bf16(bK1[kk], bQ[set][kk], sB1[set], 0, 0, 0);
      }
    __builtin_amdgcn_s_setprio(0);

    // ---- exp/pack sub0 ----
    s16x8 pf0[2];
    #pragma unroll
    for (int set = 0; set < 2; ++set) {
      union { unsigned w[4]; s16x8 h; } pu;
      #pragma unroll
      for (int rp = 0; rp < 2; ++rp) {
        float pa = EXP2F(sA0[set][2 * rp]     * 14.4269504f - 14.4269504f);
        float pb = EXP2F(sA0[set][2 * rp + 1] * 14.4269504f - 14.4269504f);
        float pc = EXP2F(sA1[set][2 * rp]     * 14.4269504f - 14.4269504f);
        float pd = EXP2F(sA1[set][2 * rp + 1] * 14.4269504f - 14.4269504f);
        pu.w[rp]     = cvtpk_bf16(pa, pb);
        pu.w[rp + 2] = cvtpk_bf16(pc, pd);
      }
      pf0[set] = pu.h;
    }

    // ---- bV sub1 ----
    s16x8 bV1[8];
    #pragma unroll
    for (int c = 0; c < 8; ++c) bV1[c] = *(const s16x8*)(vb + 4096 + c * 512);

    // ---- PV sub0 ----
    __builtin_amdgcn_s_setprio(1);
    #pragma unroll
    for (int c = 0; c < 8; ++c)
      #pragma unroll
      for (int set = 0; set < 2; ++set)
        oacc[set][c] = __builtin_amdgcn_mfma_f32_16x16x32_bf16(pf0[set], bV0[c], oacc[set][c], 0, 0, 0);
    __builtin_amdgcn_s_setprio(0);

    // ---- exp/pack sub1 ----
    s16x8 pf1[2];
    #pragma unroll
    for (int set = 0; set < 2; ++set) {
      union { unsigned w[4]; s16x8 h; } pu;
      #pragma unroll
      for (int rp = 0; rp < 2; ++rp) {
        float pa = EXP2F(sB0[set][2 * rp]     * 14.4269504f - 14.4269504f);
        float pb = EXP2F(sB0[set][2 * rp + 1] * 14.4269504f - 14.4269504f);
        float pc = EXP2F(sB1[set][2 * rp]     * 14.4269504f - 14.4269504f);
        float pd = EXP2F(sB1[set][2 * rp + 1] * 14.4269504f - 14.4269504f);
        pu.w[rp]     = cvtpk_bf16(pa, pb);
        pu.w[rp + 2] = cvtpk_bf16(pc, pd);
      }
      pf1[set] = pu.h;
    }

    // ---- PV sub1 ----
    __builtin_amdgcn_s_setprio(1);
    #pragma unroll
    for (int c = 0; c < 8; ++c)
      #pragma unroll
      for (int set = 0; set < 2; ++set)
        oacc[set][c] = __builtin_amdgcn_mfma_f32_16x16x32_bf16(pf1[set], bV1[c], oacc[set][c], 0, 0, 0);
    __builtin_amdgcn_s_setprio(0);

    __syncthreads();
  }

  // epilogue: l lives in oacc[set][7] (ones-column), col 112 -> lanes with q==0
  #pragma unroll
  for (int set = 0; set < 2; ++set) {
    const int row0 = qsup * 32 + set * 16;
    if (S == 1) {
      float linv[4];
      #pragma unroll
      for (int r = 0; r < 4; ++r) linv[r] = 1.0f / __shfl(oacc[set][7][r], g << 4);
      #pragma unroll
      for (int c = 0; c < 7; ++c) {
        const int col = c * 16 + q;
        if (col < C_DIM)
          #pragma unroll
          for (int r = 0; r < 4; ++r)
            outp[(size_t)(row0 + (g << 2) + r) * C_DIM + col] = oacc[set][c][r] * linv[r];
      }
    } else {
      if (q == 0)
        #pragma unroll
        for (int r = 0; r < 4; ++r)
          pL[(size_t)slice * N_TOT + row0 + (g << 2) + r] = oacc[set][7][r];
      #pragma unroll
      for (int c = 0; c < 7; ++c)
        #pragma unroll
        for (int r = 0; r < 4; ++r)
          pO[((size_t)slice * N_TOT + row0 + (g << 2) + r) * 112 + c * 16 + q] =
              f2bf(oacc[set][c][r]);
    }
  }
}

// ---------------- Kernel D: combine K-split partials ----------------
__global__ void k_combine(const short* __restrict__ pO, const float* __restrict__ pL,
                          float* __restrict__ out, int S) {
  const int row = blockIdx.x * 2 + (threadIdx.x >> 7);
  const int c = threadIdx.x & 127;
  float l = 0.f, o = 0.f;
  for (int s = 0; s < S; ++s) {
    l += pL[(size_t)s * N_TOT + row];
    if (c < 112) o += bf2f(pO[((size_t)s * N_TOT + row) * 112 + c]);
  }
  if (c < C_DIM) out[(size_t)row * C_DIM + c] = o / l;
}

extern "C" void kernel_launch(void* const* d_in, const int* in_sizes, int n_in,
                              void* d_out, int out_size, void* d_ws, size_t ws_size,
                              hipStream_t stream) {
  const float* anchor   = (const float*)d_in[0];  // 7168x128
  const float* positive = (const float*)d_in[1];  // 7168x128
  const float* lb_feat  = (const float*)d_in[2];  // 2048x128
  const float* lb_onehot= (const float*)d_in[3];  // 2048x100
  const float* lg1      = (const float*)d_in[5];  // 7168x100
  const float* lg2      = (const float*)d_in[6];  // 7168x100
  float* out = (float*)d_out;

  short* feats_ws = (short*)d_ws;              // 4 MB
  short* v_ws     = feats_ws + 2097152;        // 4 MB
  float* pL       = (float*)(v_ws + 2097152);  // 512 KB (8 slices max)
  short* pO       = (short*)(pL + 8 * N_TOT);  // S * 16384 * 112 * 2B

  int S = 8;
  while (S > 1 && 8912896ull + (size_t)S * N_TOT * 112 * 2 > ws_size) S >>= 1;
  const int nt2 = (512 / S) >> 1;

  k_prep<<<10440, 256, 0, stream>>>(anchor, positive, lb_feat, lb_onehot, lg1, lg2,
                                    feats_ws, v_ws, out);

  float* attn_out = out + 2301952;
  k_attn<<<128 * S, 256, 0, stream>>>(feats_ws, v_ws, pO, pL, attn_out, S, nt2);
  if (S > 1)
    k_combine<<<N_TOT / 2, 256, 0, stream>>>(pO, pL, attn_out, S);
}